// Round 1
// baseline (868.263 us; speedup 1.0000x reference)
//
#include <hip/hip_runtime.h>
#include <hip/hip_cooperative_groups.h>
#include <cmath>

namespace cg = cooperative_groups;

// Problem constants (from reference)
#define N_INPUTS 2048
#define UNITS    2048
#define L_LAYERS 8
#define FANIN    4096
#define TOTAL    18432           // N_INPUTS + L*UNITS

// Decomposition
#define NTHREADS 256
#define RK       16              // rows (k) per partial block
#define KC       (FANIN / RK)    // 256 k-chunks (partial rows)
#define JTILE    1024            // columns per partial block (256 thr * 4)
#define P_BLOCKS (2 * KC)        // 512 blocks: (j-half, k-chunk)

// Wave-parallel reduction of one partials column (KC=256 rows).
// All 64 lanes of the calling wave must participate. Returns sum in all lanes.
__device__ __forceinline__ float col_reduce(const float* __restrict__ P, int col)
{
    int lane = threadIdx.x & 63;
    float s = 0.f;
    #pragma unroll
    for (int m = 0; m < KC / 64; ++m)
        s += P[(size_t)(lane + m * 64) * UNITS + col];
    #pragma unroll
    for (int off = 32; off; off >>= 1)
        s += __shfl_down(s, off, 64);
    return __shfl(s, 0, 64);
}

// ---------------------------------------------------------------------------
// Persistent fused kernel: all 8 layers + tail in one cooperative launch.
// Per layer, per block (identical work assignment to the proven 9-dispatch
// version):
//   prefetch (issued BEFORE the grid sync of this layer, during the previous
//   iteration): 16xfloat4 W tile + int4 of node indices -> registers.
//   1. finalize owned 4 columns of slot `lay` from Pprev  (or copy x, lay==0)
//   2. gather 16 activations (recompute on-demand for current-slot indices)
//   3. FMA from prefetched W registers, store 16x1024 partial tile.
// grid.sync() provides the cross-block ordering the dispatch boundaries used
// to provide; W/index prefetch overlaps the sync + latency-bound prologue.
// ---------------------------------------------------------------------------
__global__ __launch_bounds__(NTHREADS, 2) void fused_kernel(
    const float* __restrict__ x,
    const int*   __restrict__ node_inds,
    const float* __restrict__ Ws,
    const float* __restrict__ bs,
    float*       __restrict__ outputs,
    float*       __restrict__ out,
    float*       __restrict__ P0,
    float*       __restrict__ P1)
{
    cg::grid_group grid = cg::this_grid();

    const int b     = blockIdx.x;
    const int t     = threadIdx.x;
    const int wv    = t >> 6;         // wave 0..3
    const int lane  = t & 63;
    const int jhalf = b & 1;
    const int kc    = b >> 1;
    const int jbase = jhalf * JTILE + t * 4;

    __shared__ float gsh[RK];

    float* pb[2] = { P0, P1 };

    // ---- prefetch layer 0: W tile (64 VGPRs) + node indices (wave-uniform)
    float4 w[RK];
    {
        const float4* W4 = (const float4*)(
            Ws + ((size_t)kc * RK) * UNITS + jbase);
        #pragma unroll
        for (int k = 0; k < RK; ++k)
            w[k] = W4[(size_t)k * (UNITS / 4)];
    }
    int4 nidx = *(const int4*)(node_inds + kc * RK + wv * 4);

    for (int lay = 0; lay < L_LAYERS; ++lay) {
        const float* Pprev = pb[(lay + 1) & 1];
        float*       Pcur  = pb[lay & 1];

        // Dispatch-boundary replacement. Prefetched W/idx loads issued before
        // this point complete while the barrier assembles.
        if (lay > 0) grid.sync();

        // ---- 1. finalize owned columns of slot `lay` (one column per wave)
        {
            int col = b * 4 + wv;
            if (lay == 0) {
                if (lane == 0) outputs[col] = x[col];
            } else {
                float s = col_reduce(Pprev, col);
                float y = tanhf(s + bs[(lay - 1) * UNITS + col]);
                if (lane == 0) outputs[(size_t)lay * UNITS + col] = y;
            }
        }

        // ---- 2. gather activations (4 indices per wave; idx is wave-uniform)
        {
            int idxs[4] = { nidx.x, nidx.y, nidx.z, nidx.w };
            #pragma unroll
            for (int j = 0; j < 4; ++j) {
                int q   = wv * 4 + j;
                int idx = idxs[j];
                float g;
                if (lay == 0) {
                    g = (idx < N_INPUTS) ? x[idx] : 0.f;
                } else if (idx < lay * UNITS) {
                    g = outputs[idx];
                } else if (idx < (lay + 1) * UNITS) {
                    int col = idx - lay * UNITS;
                    float s = col_reduce(Pprev, col);
                    g = tanhf(s + bs[(lay - 1) * UNITS + col]);
                } else {
                    g = 0.f;
                }
                if (lane == 0) gsh[q] = g;
            }
        }
        __syncthreads();

        // ---- 3. partial matvec from prefetched registers
        float4 a; a.x = 0.f; a.y = 0.f; a.z = 0.f; a.w = 0.f;
        #pragma unroll
        for (int k = 0; k < RK; ++k) {
            float g = gsh[k];
            a.x += g * w[k].x; a.y += g * w[k].y;
            a.z += g * w[k].z; a.w += g * w[k].w;
        }
        *(float4*)(Pcur + (size_t)kc * UNITS + jbase) = a;

        // ---- prefetch next layer's W tile + indices (overlaps next sync +
        //      next prologue). Registers are dead here; reuse them.
        if (lay + 1 < L_LAYERS) {
            const float4* W4n = (const float4*)(
                Ws + ((size_t)(lay + 1) * FANIN + (size_t)kc * RK) * UNITS + jbase);
            #pragma unroll
            for (int k = 0; k < RK; ++k)
                w[k] = W4n[(size_t)k * (UNITS / 4)];
            nidx = *(const int4*)(
                node_inds + (lay + 1) * FANIN + kc * RK + wv * 4);
        }
    }

    // ---- tail: out[col] = tanh(sum(P7[:,col]) + bs[7][col])
    grid.sync();
    {
        int col = b * 4 + wv;
        float s = col_reduce(pb[(L_LAYERS - 1) & 1], col);
        float y = tanhf(s + bs[(L_LAYERS - 1) * UNITS + col]);
        if (lane == 0) out[col] = y;
    }
}

// ---------------------------------------------------------------------------
// Fallback path (proven 9-dispatch version) — used only if the cooperative
// launch is rejected (e.g. capture restriction), so behavior degrades to the
// previous 417 µs kernel instead of failing.
// ---------------------------------------------------------------------------
__global__ __launch_bounds__(NTHREADS) void layer_kernel(
    int layer,
    const float* __restrict__ x,
    const int*   __restrict__ node_inds,
    const float* __restrict__ Ws,
    const float* __restrict__ bs,
    float*       __restrict__ outputs,
    const float* __restrict__ Pprev,
    float*       __restrict__ Pcur)
{
    const int b    = blockIdx.x;
    const int t    = threadIdx.x;
    const int wv   = t >> 6;
    const int lane = t & 63;
    const int jhalf = b & 1;
    const int kc    = b >> 1;

    __shared__ float gsh[RK];

    {
        int col = b * 4 + wv;
        if (layer == 0) {
            if (lane == 0) outputs[col] = x[col];
        } else {
            float s = col_reduce(Pprev, col);
            float y = tanhf(s + bs[(layer - 1) * UNITS + col]);
            if (lane == 0) outputs[(size_t)layer * UNITS + col] = y;
        }
    }

    #pragma unroll
    for (int j = 0; j < 4; ++j) {
        int q   = wv * 4 + j;
        int idx = node_inds[layer * FANIN + kc * RK + q];
        float g;
        if (layer == 0) {
            g = (idx < N_INPUTS) ? x[idx] : 0.f;
        } else if (idx < layer * UNITS) {
            g = outputs[idx];
        } else if (idx < (layer + 1) * UNITS) {
            int col = idx - layer * UNITS;
            float s = col_reduce(Pprev, col);
            g = tanhf(s + bs[(layer - 1) * UNITS + col]);
        } else {
            g = 0.f;
        }
        if (lane == 0) gsh[q] = g;
    }
    __syncthreads();

    const int jbase = jhalf * JTILE + t * 4;
    const float4* W4 = (const float4*)(
        Ws + ((size_t)layer * FANIN + (size_t)kc * RK) * UNITS + jbase);

    float4 a; a.x = 0.f; a.y = 0.f; a.z = 0.f; a.w = 0.f;
    #pragma unroll
    for (int k = 0; k < RK; ++k) {
        float  g = gsh[k];
        float4 wv4 = W4[(size_t)k * (UNITS / 4)];
        a.x += g * wv4.x; a.y += g * wv4.y; a.z += g * wv4.z; a.w += g * wv4.w;
    }
    *(float4*)(Pcur + (size_t)kc * UNITS + jbase) = a;
}

__global__ __launch_bounds__(NTHREADS) void tail_kernel(
    const float* __restrict__ Pprev,
    const float* __restrict__ bs,
    float*       __restrict__ out)
{
    int wv   = threadIdx.x >> 6;
    int lane = threadIdx.x & 63;
    int col  = blockIdx.x * 4 + wv;
    float s = col_reduce(Pprev, col);
    float y = tanhf(s + bs[(L_LAYERS - 1) * UNITS + col]);
    if (lane == 0) out[col] = y;
}

// ---------------------------------------------------------------------------
extern "C" void kernel_launch(void* const* d_in, const int* in_sizes, int n_in,
                              void* d_out, int out_size, void* d_ws, size_t ws_size,
                              hipStream_t stream) {
    const float* x         = (const float*)d_in[0];
    const int*   node_inds = (const int*)  d_in[1];
    const float* Ws        = (const float*)d_in[2];
    const float* bs        = (const float*)d_in[3];
    float*       out       = (float*)d_out;
    float*       ws        = (float*)d_ws;

    float* outputs = ws;                        // TOTAL floats
    float* P0      = ws + TOTAL;                // KC*UNITS floats (2 MiB)
    float* P1      = P0 + (size_t)KC * UNITS;   // KC*UNITS floats (2 MiB)

    void* args[8] = { (void*)&x, (void*)&node_inds, (void*)&Ws, (void*)&bs,
                      (void*)&outputs, (void*)&out, (void*)&P0, (void*)&P1 };

    hipError_t e = hipLaunchCooperativeKernel(
        (const void*)fused_kernel, dim3(P_BLOCKS), dim3(NTHREADS),
        args, 0, stream);

    if (e != hipSuccess) {
        // Fallback: previous 9-dispatch structure.
        float* pbuf[2] = { P0, P1 };
        for (int i = 0; i < L_LAYERS; ++i) {
            layer_kernel<<<P_BLOCKS, NTHREADS, 0, stream>>>(
                i, x, node_inds, Ws, bs, outputs,
                pbuf[(i + 1) & 1], pbuf[i & 1]);
        }
        tail_kernel<<<UNITS / 4, NTHREADS, 0, stream>>>(
            pbuf[(L_LAYERS - 1) & 1], bs, out);
    }
}

// Round 3
// 399.627 us; speedup vs baseline: 2.1727x; 2.1727x over previous
//
#include <hip/hip_runtime.h>
#include <cmath>

// Problem constants (from reference)
#define N_INPUTS 2048
#define UNITS    2048
#define L_LAYERS 8
#define FANIN    4096
#define TOTAL    18432           // N_INPUTS + L*UNITS

// Decomposition
#define NTHREADS 256
#define RK       16              // rows (k) per partial block
#define KC       (FANIN / RK)    // 256 k-chunks (partial reduction depth)
#define JPARTS   4               // column splits (was 2) -> 4 blocks/CU
#define JTILE    (UNITS / JPARTS)       // 512 columns per block
#define P_BLOCKS (KC * JPARTS)          // 1024 blocks

// ---------------------------------------------------------------------------
// Partials are stored TRANSPOSED: P[col * KC + kc].
// col_reduce is then 4 fully-coalesced 256B wave loads (lane-consecutive
// addresses), vs the old layout's 64-distinct-cacheline gather per load.
// Same values, same summation order -> bit-identical results.
// All 64 lanes of the calling wave must participate. Returns sum in all lanes.
// ---------------------------------------------------------------------------
__device__ __forceinline__ float col_reduce(const float* __restrict__ P, int col)
{
    int lane = threadIdx.x & 63;
    float s = 0.f;
    #pragma unroll
    for (int m = 0; m < KC / 64; ++m)
        s += P[(size_t)col * KC + lane + m * 64];
    #pragma unroll
    for (int off = 32; off; off >>= 1)
        s += __shfl_down(s, off, 64);
    return __shfl(s, 0, 64);
}

// ---------------------------------------------------------------------------
// Per-layer kernel (dispatch boundaries provide cross-block ordering; the
// cooperative-launch variant measured 45% SLOWER — grid.sync's device-scope
// fences + spin cost more than a dispatch boundary, and the compiler refuses
// to keep a prefetched W tile live across it).
//
// Block (kc, jp) — 1024 blocks, 4/CU:
//   0. issue its 16 x float2 W-tile loads into registers FIRST (program
//      order) so the stream's latency hides under the prologue round-trips.
//   1. finalize 2 owned columns of state slot `layer` from Pprev (waves 0,1).
//   2. gather its 16 activations (recompute current-slot ones from Pprev).
//   3. FMA from the prefetched registers, scatter-store partials transposed.
// ---------------------------------------------------------------------------
__global__ __launch_bounds__(NTHREADS, 4) void layer_kernel(
    int layer,
    const float* __restrict__ x,
    const int*   __restrict__ node_inds,
    const float* __restrict__ Ws,
    const float* __restrict__ bs,
    float*       __restrict__ outputs,
    const float* __restrict__ Pprev,
    float*       __restrict__ Pcur)
{
    const int b    = blockIdx.x;
    const int t    = threadIdx.x;
    const int wv   = t >> 6;          // wave 0..3
    const int lane = t & 63;
    const int kc   = b >> 2;          // 0..255
    const int jp   = b & 3;           // 0..3
    const int jbase = jp * JTILE + t * 2;

    __shared__ float gsh[RK];

    // ---- 0. issue W-tile loads early (16 x float2 = 32 VGPRs in flight)
    float2 w[RK];
    const float2* W2 = (const float2*)(
        Ws + ((size_t)layer * FANIN + (size_t)kc * RK) * UNITS + jbase);
    #pragma unroll
    for (int k = 0; k < RK; ++k)
        w[k] = W2[(size_t)k * (UNITS / 2)];

    // wave-uniform node indices for this block's 16 k-rows
    int4 nidx = *(const int4*)(node_inds + layer * FANIN + kc * RK + wv * 4);

    // ---- 1. finalize 2 owned columns of slot `layer` (waves 0 and 1)
    if (wv < 2) {
        int col = b * 2 + wv;         // 1024 blocks * 2 = 2048 columns
        if (layer == 0) {
            if (lane == 0) outputs[col] = x[col];
        } else {
            float s = col_reduce(Pprev, col);
            float y = tanhf(s + bs[(layer - 1) * UNITS + col]);
            if (lane == 0) outputs[(size_t)layer * UNITS + col] = y;
        }
    }

    // ---- 2. gather activations (4 indices per wave; idx is wave-uniform)
    {
        int idxs[4] = { nidx.x, nidx.y, nidx.z, nidx.w };
        #pragma unroll
        for (int j = 0; j < 4; ++j) {
            int q   = wv * 4 + j;
            int idx = idxs[j];
            float g;
            if (layer == 0) {
                g = (idx < N_INPUTS) ? x[idx] : 0.f;
            } else if (idx < layer * UNITS) {
                g = outputs[idx];
            } else if (idx < (layer + 1) * UNITS) {
                int col = idx - layer * UNITS;
                float s = col_reduce(Pprev, col);
                g = tanhf(s + bs[(layer - 1) * UNITS + col]);
            } else {
                g = 0.f;
            }
            if (lane == 0) gsh[q] = g;
        }
    }
    __syncthreads();

    // ---- 3. partial matvec from prefetched registers; transposed store
    float ax = 0.f, ay = 0.f;
    #pragma unroll
    for (int k = 0; k < RK; ++k) {
        float g = gsh[k];
        ax += g * w[k].x;
        ay += g * w[k].y;
    }
    Pcur[(size_t)jbase       * KC + kc] = ax;
    Pcur[(size_t)(jbase + 1) * KC + kc] = ay;
}

// ---------------------------------------------------------------------------
// Tail: out[col] = tanh(sum over kc of P7[col][kc] + bs[7][col])
// 512 blocks x 4 waves -> one column per wave, covers all 2048 columns.
// ---------------------------------------------------------------------------
__global__ __launch_bounds__(NTHREADS) void tail_kernel(
    const float* __restrict__ Pprev,
    const float* __restrict__ bs,
    float*       __restrict__ out)
{
    int wv   = threadIdx.x >> 6;
    int lane = threadIdx.x & 63;
    int col  = blockIdx.x * 4 + wv;
    float s = col_reduce(Pprev, col);
    float y = tanhf(s + bs[(L_LAYERS - 1) * UNITS + col]);
    if (lane == 0) out[col] = y;
}

// ---------------------------------------------------------------------------
extern "C" void kernel_launch(void* const* d_in, const int* in_sizes, int n_in,
                              void* d_out, int out_size, void* d_ws, size_t ws_size,
                              hipStream_t stream) {
    const float* x         = (const float*)d_in[0];
    const int*   node_inds = (const int*)  d_in[1];
    const float* Ws        = (const float*)d_in[2];
    const float* bs        = (const float*)d_in[3];
    float*       out       = (float*)d_out;
    float*       ws        = (float*)d_ws;

    float* outputs = ws;                        // TOTAL floats
    float* P0      = ws + TOTAL;                // KC*UNITS floats (2 MiB)
    float* P1      = P0 + (size_t)KC * UNITS;   // KC*UNITS floats (2 MiB)

    float* pbuf[2] = { P0, P1 };

    for (int i = 0; i < L_LAYERS; ++i) {
        layer_kernel<<<P_BLOCKS, NTHREADS, 0, stream>>>(
            i, x, node_inds, Ws, bs, outputs,
            pbuf[(i + 1) & 1],   // Pprev (unused when i==0)
            pbuf[i & 1]);        // Pcur
    }
    tail_kernel<<<UNITS / 4, NTHREADS, 0, stream>>>(
        pbuf[(L_LAYERS - 1) & 1], bs, out);
}